// Round 14
// baseline (5563.697 us; speedup 1.0000x reference)
//
#include <hip/hip_runtime.h>

// ===== BDH forward on MI355X — R14: A-frag hoist (fused 3-panel MMA) in g2/g1/g4a =====
// R13 (4687us): g2 LDS-read-bound — mma64x2 x3 re-read A-frags each call
// (72 b128/wave/K-step). R14: fused mma_a2b3 reads A once per kk (40 b128),
// and g1/g4a adopt the same 1-A x 3-B block shape (grid 16x11x4, 80KB LDS).
// Bit-identical math everywhere.

typedef unsigned short u16;
typedef unsigned int   u32;
typedef __attribute__((ext_vector_type(8))) short bf8;
typedef __attribute__((ext_vector_type(4))) float f4;

#define T_  2048
#define D_  256
#define NH_ 4
#define NN_ 4096
#define NLAYER 6

// ---- workspace layout (bytes); per-b activation buffers ----
#define CSA_OFF  ((size_t)0)                    // float2 [16][2048]  coarse-t trig
#define CSB_OFF  (CSA_OFF  + 262144)            // float2 [128][2048] fine-t trig
#define ETH_OFF  (CSB_OFF  + 2097152)           // bf16 [4][4096][256] enc^T hi
#define ETL_OFF  (ETH_OFF  + 8388608)
#define EVH_OFF  (ETL_OFF  + 8388608)
#define EVL_OFF  (EVH_OFF  + 8388608)
#define DTH_OFF  (EVL_OFF  + 8388608)           // bf16 [4][256][4096] dec^T hi
#define DTL_OFF  (DTH_OFF  + 8388608)
#define LMH_OFF  (DTL_OFF  + 8388608)           // bf16 [256][256] lm^T
#define LML_OFF  (LMH_OFF  + 131072)
#define X_OFF    (LML_OFF  + 131072)            // f32  [2048][256] x (per-b)
#define XBH_OFF  (X_OFF    + 2097152)           // bf16 [2048][256] (per-b)
#define XBL_OFF  (XBH_OFF  + 1048576)
#define XBTH_OFF (XBL_OFF  + 1048576)           // bf16 [256][2048] (per-b)
#define XBTL_OFF (XBTH_OFF + 1048576)
#define QRH_OFF  (XBTL_OFF + 1048576)           // bf16 [4][2048][4096] QR/xy hi (per-b)
#define QRL_OFF  (QRH_OFF  + 67108864)
#define SH_OFF   (QRL_OFF  + 67108864)          // bf16 [4][136][16384] S hi (per-b); part f32 overlays
#define SL_OFF   (SH_OFF   + 17825792)          // FREED (no S-lo) -> f32 yKV partial-1
#define YKV_OFF  (SL_OFF   + 17825792)          // f32  [4][2048][256] yKV partial-0 (per-b)
#define YKBH_OFF (YKV_OFF  + 8388608)           // bf16 ln(yKV) hi (per-b)
#define YKBL_OFF (YKBH_OFF + 4194304)
#define IDX_END  (YKBL_OFF + 4194304)
#define WS_NEED  (IDX_END  + 16384)             // = 245,907,456 < 253,902,848 proven

// ---------- helpers ----------
__device__ __forceinline__ u16 f2b(float f) {               // RTNE f32->bf16
  u32 u = __builtin_bit_cast(u32, f);
  u32 r = u + 0x7fffu + ((u >> 16) & 1u);
  return (u16)(r >> 16);
}
__device__ __forceinline__ float b2f(u16 h) {
  u32 u = ((u32)h) << 16;
  return __builtin_bit_cast(float, u);
}
__device__ __forceinline__ void split2(float q0, float q1, u32& hi, u32& lo) {
  u16 h0 = f2b(q0), h1 = f2b(q1);
  u16 l0 = f2b(q0 - b2f(h0)), l1 = f2b(q1 - b2f(h1));
  hi = (u32)h0 | ((u32)h1 << 16);
  lo = (u32)l0 | ((u32)l1 << 16);
}
__device__ __forceinline__ float wsum(float v) {
#pragma unroll
  for (int o = 32; o; o >>= 1) v += __shfl_xor(v, o, 64);
  return v;
}
// trig from factored tables: pp = pair index [0,2048), t = time [0,2048)
__device__ __forceinline__ float2 trig_ct(const float2* csA, const float2* csB, int t, int pp) {
  float2 a = csA[(t >> 7) * 2048 + pp];
  float2 b = csB[(t & 127) * 2048 + pp];
  return make_float2(a.x * b.x - a.y * b.y, a.x * b.y + a.y * b.x);
}
__device__ __forceinline__ void gld16(const u16* g, short* l) {
  __builtin_amdgcn_global_load_lds(
      (const __attribute__((address_space(1))) u32*)g,
      (__attribute__((address_space(3))) u32*)l, 16, 0, 0);
}
// stage 128x64 bf16 tile into LDS [128][64], XOR-swizzled (T2, both-sides):
// linear LDS dest (global_load_lds req) + pre-swizzled global source col.
__device__ __forceinline__ void stage_t(const u16* g, int lda, short* s, int wid, int lane) {
  int r8 = lane >> 3;                       // 0..7 rows within 8-row stripe
  int c8 = ((lane & 7) ^ r8) * 8;           // pre-swizzled source column slot
#pragma unroll
  for (int j = 0; j < 4; ++j) {
    int row = wid * 32 + j * 8;             // multiple of 8 -> (row+r8)&7 == r8
    gld16(g + (size_t)(row + r8) * lda + c8, s + row * 64);
  }
}
// BK=64 step, 3-term split: 96 MFMA (hh, lh, hl) — used by g5 only
__device__ __forceinline__ void mma64x3(const short* AsH, const short* AsL, const short* BsH,
                                        const short* BsL, int wr, int wc, int lane,
                                        f4 acc[4][4]) {
  int r15 = lane & 15, hi = lane >> 4;
  int sw = (r15 & 7) << 3;
#pragma unroll
  for (int kk = 0; kk < 2; ++kk) {
    int ko = (kk * 32 + hi * 8) ^ sw;
    bf8 ah[4], al[4], bh[4], bl[4];
#pragma unroll
    for (int m = 0; m < 4; ++m) {
      int off = (wr * 64 + m * 16 + r15) * 64 + ko;
      ah[m] = *(const bf8*)(AsH + off);
      al[m] = *(const bf8*)(AsL + off);
    }
#pragma unroll
    for (int n = 0; n < 4; ++n) {
      int off = (wc * 64 + n * 16 + r15) * 64 + ko;
      bh[n] = *(const bf8*)(BsH + off);
      bl[n] = *(const bf8*)(BsL + off);
    }
#pragma unroll
    for (int m = 0; m < 4; ++m)
#pragma unroll
      for (int n = 0; n < 4; ++n) {
        acc[m][n] = __builtin_amdgcn_mfma_f32_16x16x32_bf16(ah[m], bh[n], acc[m][n], 0, 0, 0);
        acc[m][n] = __builtin_amdgcn_mfma_f32_16x16x32_bf16(al[m], bh[n], acc[m][n], 0, 0, 0);
        acc[m][n] = __builtin_amdgcn_mfma_f32_16x16x32_bf16(ah[m], bl[n], acc[m][n], 0, 0, 0);
      }
  }
}
// BK=64 step, 2-term A-split: acc += (Ah+Al)*Bh^T  (64 MFMA) — g4b
__device__ __forceinline__ void mma64x2(const short* AsH, const short* AsL, const short* BsH,
                                        int wr, int wc, int lane, f4 acc[4][4]) {
  int r15 = lane & 15, hi = lane >> 4;
  int sw = (r15 & 7) << 3;
#pragma unroll
  for (int kk = 0; kk < 2; ++kk) {
    int ko = (kk * 32 + hi * 8) ^ sw;
    bf8 ah[4], al[4], bh[4];
#pragma unroll
    for (int m = 0; m < 4; ++m) {
      int off = (wr * 64 + m * 16 + r15) * 64 + ko;
      ah[m] = *(const bf8*)(AsH + off);
      al[m] = *(const bf8*)(AsL + off);
    }
#pragma unroll
    for (int n = 0; n < 4; ++n)
      bh[n] = *(const bf8*)(BsH + (wc * 64 + n * 16 + r15) * 64 + ko);
#pragma unroll
    for (int m = 0; m < 4; ++m)
#pragma unroll
      for (int n = 0; n < 4; ++n) {
        acc[m][n] = __builtin_amdgcn_mfma_f32_16x16x32_bf16(ah[m], bh[n], acc[m][n], 0, 0, 0);
        acc[m][n] = __builtin_amdgcn_mfma_f32_16x16x32_bf16(al[m], bh[n], acc[m][n], 0, 0, 0);
      }
  }
}
// BK=64 step, fused 2-term x 3 B-panels: A-frags read ONCE per kk (T: LDS-read cut)
__device__ __forceinline__ void mma_a2b3(const short* AsH, const short* AsL, const short* B0,
                                         const short* B1, const short* B2, bool has1, bool has2,
                                         int wr, int wc, int lane, f4 acc0[4][4], f4 acc1[4][4],
                                         f4 acc2[4][4]) {
  int r15 = lane & 15, hi = lane >> 4;
  int sw = (r15 & 7) << 3;
#pragma unroll
  for (int kk = 0; kk < 2; ++kk) {
    int ko = (kk * 32 + hi * 8) ^ sw;
    bf8 ah[4], al[4], bh[4];
#pragma unroll
    for (int m = 0; m < 4; ++m) {
      int off = (wr * 64 + m * 16 + r15) * 64 + ko;
      ah[m] = *(const bf8*)(AsH + off);
      al[m] = *(const bf8*)(AsL + off);
    }
#pragma unroll
    for (int n = 0; n < 4; ++n) bh[n] = *(const bf8*)(B0 + (wc * 64 + n * 16 + r15) * 64 + ko);
#pragma unroll
    for (int m = 0; m < 4; ++m)
#pragma unroll
      for (int n = 0; n < 4; ++n) {
        acc0[m][n] = __builtin_amdgcn_mfma_f32_16x16x32_bf16(ah[m], bh[n], acc0[m][n], 0, 0, 0);
        acc0[m][n] = __builtin_amdgcn_mfma_f32_16x16x32_bf16(al[m], bh[n], acc0[m][n], 0, 0, 0);
      }
    if (has1) {
#pragma unroll
      for (int n = 0; n < 4; ++n) bh[n] = *(const bf8*)(B1 + (wc * 64 + n * 16 + r15) * 64 + ko);
#pragma unroll
      for (int m = 0; m < 4; ++m)
#pragma unroll
        for (int n = 0; n < 4; ++n) {
          acc1[m][n] = __builtin_amdgcn_mfma_f32_16x16x32_bf16(ah[m], bh[n], acc1[m][n], 0, 0, 0);
          acc1[m][n] = __builtin_amdgcn_mfma_f32_16x16x32_bf16(al[m], bh[n], acc1[m][n], 0, 0, 0);
        }
    }
    if (has2) {
#pragma unroll
      for (int n = 0; n < 4; ++n) bh[n] = *(const bf8*)(B2 + (wc * 64 + n * 16 + r15) * 64 + ko);
#pragma unroll
      for (int m = 0; m < 4; ++m)
#pragma unroll
        for (int n = 0; n < 4; ++n) {
          acc2[m][n] = __builtin_amdgcn_mfma_f32_16x16x32_bf16(ah[m], bh[n], acc2[m][n], 0, 0, 0);
          acc2[m][n] = __builtin_amdgcn_mfma_f32_16x16x32_bf16(al[m], bh[n], acc2[m][n], 0, 0, 0);
        }
    }
  }
}
// BK=64 step, 2-term B-split: acc += Ah*(Bh+Bl)^T  (64 MFMA) — g3
__device__ __forceinline__ void mma64x2b(const short* AsH, const short* BsH, const short* BsL,
                                         int wr, int wc, int lane, f4 acc[4][4]) {
  int r15 = lane & 15, hi = lane >> 4;
  int sw = (r15 & 7) << 3;
#pragma unroll
  for (int kk = 0; kk < 2; ++kk) {
    int ko = (kk * 32 + hi * 8) ^ sw;
    bf8 ah[4], bh[4], bl[4];
#pragma unroll
    for (int m = 0; m < 4; ++m)
      ah[m] = *(const bf8*)(AsH + (wr * 64 + m * 16 + r15) * 64 + ko);
#pragma unroll
    for (int n = 0; n < 4; ++n) {
      int off = (wc * 64 + n * 16 + r15) * 64 + ko;
      bh[n] = *(const bf8*)(BsH + off);
      bl[n] = *(const bf8*)(BsL + off);
    }
#pragma unroll
    for (int m = 0; m < 4; ++m)
#pragma unroll
      for (int n = 0; n < 4; ++n) {
        acc[m][n] = __builtin_amdgcn_mfma_f32_16x16x32_bf16(ah[m], bh[n], acc[m][n], 0, 0, 0);
        acc[m][n] = __builtin_amdgcn_mfma_f32_16x16x32_bf16(ah[m], bl[n], acc[m][n], 0, 0, 0);
      }
  }
}
__device__ __forceinline__ void acc_zero(f4 acc[4][4]) {
#pragma unroll
  for (int m = 0; m < 4; ++m)
#pragma unroll
    for (int n = 0; n < 4; ++n)
#pragma unroll
      for (int j = 0; j < 4; ++j) acc[m][n][j] = 0.0f;
}
// C frag (col=lane&15, row=(lane>>4)*4+j) -> f32 LDS bounce [128][128] (g5)
__device__ __forceinline__ void acc_store_f32(float* F, f4 acc[4][4], int wr, int wc, int lane,
                                              bool relu) {
  int r15 = lane & 15, q = lane >> 4;
#pragma unroll
  for (int m = 0; m < 4; ++m)
#pragma unroll
    for (int n = 0; n < 4; ++n)
#pragma unroll
      for (int j = 0; j < 4; ++j) {
        float v = acc[m][n][j];
        if (relu) v = fmaxf(v, 0.0f);
        F[(wr * 64 + m * 16 + q * 4 + j) * 128 + wc * 64 + n * 16 + r15] = v;
      }
}
// half-store (pass p writes waves wr==p) into [64][128] f32 bounce (32KB)
__device__ __forceinline__ void acc_store_half(float* F, f4 acc[4][4], int pass, int wr, int wc,
                                               int lane, bool relu) {
  if (wr != pass) return;
  int r15 = lane & 15, q = lane >> 4;
#pragma unroll
  for (int m = 0; m < 4; ++m)
#pragma unroll
    for (int n = 0; n < 4; ++n)
#pragma unroll
      for (int j = 0; j < 4; ++j) {
        float v = acc[m][n][j];
        if (relu) v = fmaxf(v, 0.0f);
        F[(m * 16 + q * 4 + j) * 128 + wc * 64 + n * 16 + r15] = v;
      }
}

// ---------- prep kernels ----------
// factored trig tables, f64-built. 144 rows x 2048 pairs.
__global__ __launch_bounds__(256) void k_costab(float2* csA, float2* csB) {
  int id = blockIdx.x * 256 + threadIdx.x;  // 1152 blocks -> 294912
  int r = id >> 11, p = id & 2047;
  double freq = exp2(-(double)p / 128.0) * 0.15915494309189533577;  // theta=2^16, incl 1/(2pi)
  int t = (r < 16) ? (r * 128) : (r - 16);
  double ph = fmod((double)t * freq, 1.0);
  double ang = ph * 6.2831853071795864769;
  float2 v = make_float2((float)cos(ang), (float)sin(ang));
  if (r < 16) csA[r * 2048 + p] = v;
  else        csB[(r - 16) * 2048 + p] = v;
}

// transpose+cast to hi/lo: in f32 (R,C) -> out bf16 (C,R) x2
__global__ __launch_bounds__(256) void k_tcast2(const float* __restrict__ in,
                                                u16* __restrict__ outH, u16* __restrict__ outL,
                                                int R, int C) {
  __shared__ float tl[32][33];
  size_t bo = (size_t)blockIdx.z * R * C;
  int tx = threadIdx.x, ty = threadIdx.y;
  int c = blockIdx.x * 32 + tx, r0 = blockIdx.y * 32 + ty;
#pragma unroll
  for (int k = 0; k < 32; k += 8) tl[ty + k][tx] = in[bo + (size_t)(r0 + k) * C + c];
  __syncthreads();
  int rr = blockIdx.y * 32 + tx, cc0 = blockIdx.x * 32 + ty;
#pragma unroll
  for (int k = 0; k < 32; k += 8) {
    float v = tl[tx][ty + k];
    u16 h = f2b(v);
    outH[bo + (size_t)(cc0 + k) * R + rr] = h;
    outL[bo + (size_t)(cc0 + k) * R + rr] = f2b(v - b2f(h));
  }
}

// ln(embed[idx]) for batch b -> x (f32, per-b), xb hi/lo (per-b). 512 blocks.
__global__ __launch_bounds__(256) void k_ln_embed(const int* __restrict__ idx,
                                                  const float* __restrict__ embed, int b,
                                                  float* __restrict__ x, u16* __restrict__ xbH,
                                                  u16* __restrict__ xbL) {
  int lane = threadIdx.x & 63, wid = threadIdx.x >> 6;
  int r = blockIdx.x * 4 + wid;                 // [0,2048)
  int id = idx[b * T_ + r] & 255;
  float4 v = ((const float4*)(embed + (size_t)id * 256))[lane];
  float m = wsum(v.x + v.y + v.z + v.w) * (1.0f / 256.0f);
  float d0 = v.x - m, d1 = v.y - m, d2 = v.z - m, d3 = v.w - m;
  float var = wsum(d0 * d0 + d1 * d1 + d2 * d2 + d3 * d3) * (1.0f / 256.0f);
  float rs = 1.0f / sqrtf(var + 1e-5f);
  float y0 = d0 * rs, y1 = d1 * rs, y2 = d2 * rs, y3 = d3 * rs;
  ((float4*)(x + (size_t)r * 256))[lane] = make_float4(y0, y1, y2, y3);
  ushort4 oh, ol;
  oh.x = f2b(y0); ol.x = f2b(y0 - b2f(oh.x));
  oh.y = f2b(y1); ol.y = f2b(y1 - b2f(oh.y));
  oh.z = f2b(y2); ol.z = f2b(y2 - b2f(oh.z));
  oh.w = f2b(y3); ol.w = f2b(y3 - b2f(oh.w));
  ((ushort4*)(xbH + (size_t)r * 256))[lane] = oh;
  ((ushort4*)(xbL + (size_t)r * 256))[lane] = ol;
}

// per-b transpose xb -> xbT ([256][2048]). 2048 blocks.
__global__ __launch_bounds__(256) void k_xbt(const u16* __restrict__ xbH,
                                             const u16* __restrict__ xbL,
                                             u16* __restrict__ xbTH, u16* __restrict__ xbTL) {
  int id = blockIdx.x * 256 + threadIdx.x;      // 256*2048
  int t = id & 2047, d = id >> 11;
  size_t src = (size_t)t * 256 + d;
  xbTH[id] = xbH[src];
  xbTL[id] = xbL[src];
}

// ---------- GEMM kernels ----------
// 96KB double-buffer preamble (g3/g4b)
#define GEMM_PRE2D                                                      \
  __shared__ short smd[49152];                                          \
  float* bounce = (float*)smd;                                          \
  int tid = threadIdx.x;                                                \
  int lane = tid & 63, wid = tid >> 6;                                  \
  int wr = wid >> 1, wc = wid & 1;                                      \
  f4 acc[4][4];                                                         \
  acc_zero(acc);

// 80KB fused 3-panel preamble (g1/g2/g4a)
#define GEMM_PRE3P                                                      \
  __shared__ short smp[40960];                                          \
  short* AsH = smp;                                                     \
  short* AsL = smp + 8192;                                              \
  short* Bs0 = smp + 16384;                                             \
  short* Bs1 = smp + 24576;                                             \
  short* Bs2 = smp + 32768;                                             \
  float* bounce = (float*)smp;                                          \
  int tid = threadIdx.x;                                                \
  int lane = tid & 63, wid = tid >> 6;                                  \
  int wr = wid >> 1, wc = wid & 1;                                      \
  f4 acc0[4][4], acc1[4][4], acc2[4][4];                                \
  acc_zero(acc0); acc_zero(acc1); acc_zero(acc2);

// G1: x_sparse=relu(xb@enc_hi[h]) -> rope -> QR hi/lo.  Fused 3 B-panels.
// grid(16,11,4): gy covers jt = 3gy..min(3gy+2,31).  per-b.
__global__ __launch_bounds__(256) void k_g1(const u16* __restrict__ xbH, const u16* __restrict__ xbL,
                                            const u16* __restrict__ etH,
                                            const float2* __restrict__ csA,
                                            const float2* __restrict__ csB,
                                            u16* __restrict__ QRH, u16* __restrict__ QRL) {
  GEMM_PRE3P
  int it = blockIdx.x, gy = blockIdx.y, h = blockIdx.z;
  int j0 = gy * 3;
  int np = (32 - j0 < 3) ? (32 - j0) : 3;
  size_t ao = (size_t)it * 128 * 256;
  size_t bo = (size_t)h * NN_ * 256 + (size_t)j0 * 128 * 256;
  for (int kb = 0; kb < 4; ++kb) {
    stage_t(xbH + ao + kb * 64, 256, AsH, wid, lane);
    stage_t(xbL + ao + kb * 64, 256, AsL, wid, lane);
    stage_t(etH + bo + kb * 64, 256, Bs0, wid, lane);
    if (np > 1) stage_t(etH + bo + 32768 + kb * 64, 256, Bs1, wid, lane);
    if (np > 2) stage_t(etH + bo + 65536 + kb * 64, 256, Bs2, wid, lane);
    __syncthreads();
    mma_a2b3(AsH, AsL, Bs0, Bs1, Bs2, np > 1, np > 2, wr, wc, lane, acc0, acc1, acc2);
    __syncthreads();
  }
#pragma unroll
  for (int jb = 0; jb < 3; ++jb) {
    if (jb >= np) break;
    int jt = j0 + jb;
#pragma unroll
    for (int pass = 0; pass < 2; ++pass) {
      if (jb == 0) acc_store_half(bounce, acc0, pass, wr, wc, lane, true);
      else if (jb == 1) acc_store_half(bounce, acc1, pass, wr, wc, lane, true);
      else acc_store_half(bounce, acc2, pass, wr, wc, lane, true);
      __syncthreads();
      for (int w = 0; w < 16; ++w) {
        int e = w * 256 + tid;                 // 4096 pairs
        int rrel = e >> 6, p = e & 63;
        float v0 = bounce[rrel * 128 + 2 * p], v1 = bounce[rrel * 128 + 2 * p + 1];
        int t = it * 128 + pass * 64 + rrel, pp = jt * 64 + p;
        float2 c = trig_ct(csA, csB, t, pp);
        float q0 = v0 * c.x - v1 * c.y;
        float q1 = v1 * c.x + v0 * c.y;
        u32 hi, lo;
        split2(q0, q1, hi, lo);
        size_t u32b = (size_t)(h * T_ + t) * 2048 + pp;
        ((u32*)QRH)[u32b] = hi;
        ((u32*)QRL)[u32b] = lo;
      }
      __syncthreads();
    }
  }
}

// G2: S = mask((Qh+Ql)@Qh^T), lower-tri, row-triple blocks (A-panel x 3 B-panels).
// 1D grid 204 per b (4h x 51 groups), bijective XCD chunk (m204).  80KB LDS.
__global__ __launch_bounds__(256) void k_g2(const u16* __restrict__ QRH,
                                            const u16* __restrict__ QRL,
                                            u16* __restrict__ SpH) {
  GEMM_PRE3P
  // bijective XCD chunking for N=204: q=25, r=4 (m204)
  int orig = blockIdx.x;
  int xcd = orig & 7, sub = orig >> 3;
  int lb = (xcd < 4 ? xcd * 26 : 104 + (xcd - 4) * 25) + sub;
  int h = lb / 51;
  int rem = lb % 51, i = 0;
  while (rem >= (i + 3) / 3) { rem -= (i + 3) / 3; ++i; }
  int j0 = rem * 3, j1 = j0 + 1, j2 = j0 + 2;
  bool has1 = (j1 <= i), has2 = (j2 <= i);
  size_t base = (size_t)h * T_ * NN_;
  size_t ao = base + (size_t)i * 128 * NN_;
  size_t bo0 = base + (size_t)j0 * 128 * NN_;
  size_t bo1 = base + (size_t)j1 * 128 * NN_;
  size_t bo2 = base + (size_t)j2 * 128 * NN_;
  for (int kb = 0; kb < 64; ++kb) {
    stage_t(QRH + ao + kb * 64, NN_, AsH, wid, lane);
    stage_t(QRL + ao + kb * 64, NN_, AsL, wid, lane);
    stage_t(QRH + bo0 + kb * 64, NN_, Bs0, wid, lane);
    if (has1) stage_t(QRH + bo1 + kb * 64, NN_, Bs1, wid, lane);
    if (has2) stage_t(QRH + bo2 + kb * 64, NN_, Bs2, wid, lane);
    __syncthreads();
    mma_a2b3(AsH, AsL, Bs0, Bs1, Bs2, has1, has2, wr, wc, lane, acc0, acc1, acc2);
    __syncthreads();
  }
  // epilogue: up to 3 output blocks, 2-pass bounce each
#pragma unroll
  for (int jb = 0; jb < 3; ++jb) {
    if (jb == 1 && !has1) break;
    if (jb == 2 && !has2) break;
    int j = j0 + jb;
    size_t dblk = ((size_t)h * 136 + (size_t)i * (i + 1) / 2 + j) * 16384;
    bool diag = (i == j);
#pragma unroll
    for (int pass = 0; pass < 2; ++pass) {
      if (jb == 0) acc_store_half(bounce, acc0, pass, wr, wc, lane, false);
      else if (jb == 1) acc_store_half(bounce, acc1, pass, wr, wc, lane, false);
      else acc_store_half(bounce, acc2, pass, wr, wc, lane, false);
      __syncthreads();
      for (int w = 0; w < 16; ++w) {
        int e = w * 256 + tid;
        int rrel = e >> 6, p = e & 63;
        int row = pass * 64 + rrel;
        float s0 = bounce[rrel * 128 + 2 * p], s1 = bounce[rrel * 128 + 2 * p + 1];
        if (diag) {  // strictly lower: col < row
          if (2 * p >= row) s0 = 0.0f;
          if (2 * p + 1 >= row) s1 = 0.0f;
        }
        u32 hi = (u32)f2b(s0) | ((u32)f2b(s1) << 16);
        ((u32*)SpH)[(dblk >> 1) + row * 64 + p] = hi;
      }
      __syncthreads();
    }
  }
}

// G3: yKV_partial = S_hi @ (xh+xl), split-K x2, double-buffered.
// grid(16,2,8): z = h + 4*ks.  per-b.
__global__ __launch_bounds__(256) void k_g3(const u16* __restrict__ SpH,
                                            const u16* __restrict__ xbTH,
                                            const u16* __restrict__ xbTL,
                                            float* __restrict__ yKV0,
                                            float* __restrict__ yKV1) {
  GEMM_PRE2D
  int i = blockIdx.x, jt = blockIdx.y;
  int h = blockIdx.z & 3, ks = blockIdx.z >> 2;
  size_t tri = (size_t)h * 136 + (size_t)i * (i + 1) / 2;
  size_t bo = (size_t)jt * 128 * T_;
  int k0 = ks * (i + 1), k1 = (ks + 1) * (i + 1);   // half-step range
  {  // prologue
    size_t aoff = (tri + (k0 >> 1)) * 16384 + (k0 & 1) * 64;
    stage_t(SpH + aoff, 128, smd, wid, lane);
    stage_t(xbTH + bo + k0 * 64, T_, smd + 8192, wid, lane);
    stage_t(xbTL + bo + k0 * 64, T_, smd + 16384, wid, lane);
  }
  for (int kb = k0; kb < k1; ++kb) {
    short* cur = smd + ((kb - k0) & 1) * 24576;
    __syncthreads();
    if (kb + 1 < k1) {
      short* nxt = smd + ((kb + 1 - k0) & 1) * 24576;
      size_t aoff = (tri + ((kb + 1) >> 1)) * 16384 + ((kb + 1) & 1) * 64;
      stage_t(SpH + aoff, 128, nxt, wid, lane);
      stage_t(xbTH + bo + (kb + 1) * 64, T_, nxt + 8192, wid, lane);
      stage_t(xbTL + bo + (kb + 1) * 64, T_, nxt + 16384, wid, lane);
    }
    mma64x2b(cur, cur + 8192, cur + 16384, wr, wc, lane, acc);
  }
  __syncthreads();
  float* yout = ks ? yKV1 : yKV0;
#pragma unroll
  for (int pass = 0; pass < 2; ++pass) {
    acc_store_half(bounce, acc, pass, wr, wc, lane, false);
    __syncthreads();
    for (int w = 0; w < 32; ++w) {
      int e = w * 256 + tid;                 // 8192 elems
      int row = e >> 7, col = e & 127;
      yout[((size_t)h * T_ + i * 128 + pass * 64 + row) * 256 + jt * 128 + col] =
          bounce[row * 128 + col];
    }
    __syncthreads();
  }
}

// LN over f32 rows of 256 (sum of 2 partials) -> hi/lo bf16.  2048 blocks, per-b.
__global__ __launch_bounds__(256) void k_ln_f32(const float* __restrict__ in0,
                                                const float* __restrict__ in1,
                                                u16* __restrict__ outH, u16* __restrict__ outL) {
  int lane = threadIdx.x & 63, wid = threadIdx.x >> 6;
  int r = blockIdx.x * 4 + wid;
  float4 a = ((const float4*)(in0 + (size_t)r * 256))[lane];
  float4 b = ((const float4*)(in1 + (size_t)r * 256))[lane];
  float v0 = a.x + b.x, v1 = a.y + b.y, v2 = a.z + b.z, v3 = a.w + b.w;
  float m = wsum(v0 + v1 + v2 + v3) * (1.0f / 256.0f);
  float d0 = v0 - m, d1 = v1 - m, d2 = v2 - m, d3 = v3 - m;
  float var = wsum(d0 * d0 + d1 * d1 + d2 * d2 + d3 * d3) * (1.0f / 256.0f);
  float rs = 1.0f / sqrtf(var + 1e-5f);
  float y0 = d0 * rs, y1 = d1 * rs, y2 = d2 * rs, y3 = d3 * rs;
  ushort4 oh, ol;
  oh.x = f2b(y0); ol.x = f2b(y0 - b2f(oh.x));
  oh.y = f2b(y1); ol.y = f2b(y1 - b2f(oh.y));
  oh.z = f2b(y2); ol.z = f2b(y2 - b2f(oh.z));
  oh.w = f2b(y3); ol.w = f2b(y3 - b2f(oh.w));
  ((ushort4*)(outH + (size_t)r * 256))[lane] = oh;
  ((ushort4*)(outL + (size_t)r * 256))[lane] = ol;
}

// G4a: y_sparse=relu((ykh+ykl)@encv_hi[h]); gate by invrope(QR h+l); xy -> QR hi/lo.
// Fused 3 B-panels, grid(16,11,4).  per-b.
__global__ __launch_bounds__(256) void k_g4a(const u16* __restrict__ ykH,
                                             const u16* __restrict__ ykL,
                                             const u16* __restrict__ evH,
                                             const float2* __restrict__ csA,
                                             const float2* __restrict__ csB,
                                             u16* __restrict__ QRH, u16* __restrict__ QRL) {
  GEMM_PRE3P
  int it = blockIdx.x, gy = blockIdx.y, h = blockIdx.z;
  int j0 = gy * 3;
  int np = (32 - j0 < 3) ? (32 - j0) : 3;
  int t0 = it * 128;
  size_t ao = (size_t)(h * T_ + t0) * 256;
  size_t bo = (size_t)h * NN_ * 256 + (size_t)j0 * 128 * 256;
  for (int kb = 0; kb < 4; ++kb) {
    stage_t(ykH + ao + kb * 64, 256, AsH, wid, lane);
    stage_t(ykL + ao + kb * 64, 256, AsL, wid, lane);
    stage_t(evH + bo + kb * 64, 256, Bs0, wid, lane);
    if (np > 1) stage_t(evH + bo + 32768 + kb * 64, 256, Bs1, wid, lane);
    if (np > 2) stage_t(evH + bo + 65536 + kb * 64, 256, Bs2, wid, lane);
    __syncthreads();
    mma_a2b3(AsH, AsL, Bs0, Bs1, Bs2, np > 1, np > 2, wr, wc, lane, acc0, acc1, acc2);
    __syncthreads();
  }
#pragma unroll
  for (int jb = 0; jb < 3; ++jb) {
    if (jb >= np) break;
    int jt = j0 + jb;
#pragma unroll
    for (int pass = 0; pass < 2; ++pass) {
      if (jb == 0) acc_store_half(bounce, acc0, pass, wr, wc, lane, true);
      else if (jb == 1) acc_store_half(bounce, acc1, pass, wr, wc, lane, true);
      else acc_store_half(bounce, acc2, pass, wr, wc, lane, true);
      __syncthreads();
      for (int w = 0; w < 16; ++w) {
        int e = w * 256 + tid;
        int rrel = e >> 6, p = e & 63;
        float ys0 = bounce[rrel * 128 + 2 * p], ys1 = bounce[rrel * 128 + 2 * p + 1];
        int t = t0 + pass * 64 + rrel, pp = jt * 64 + p;
        size_t u32b = (size_t)(h * T_ + t) * 2048 + pp;
        u32 qh = ((const u32*)QRH)[u32b], ql = ((const u32*)QRL)[u32b];
        float qe = b2f((u16)(qh & 0xffff)) + b2f((u16)(ql & 0xffff));
        float qo = b2f((u16)(qh >> 16)) + b2f((u16)(ql >> 16));
        float2 c = trig_ct(csA, csB, t, pp);
        float xe = fmaxf(qe * c.x + qo * c.y, 0.0f);  // inverse rotation; x_sparse >= 0
        float xo = fmaxf(qo * c.x - qe * c.y, 0.0f);
        u32 hi, lo;
        split2(ys0 * xe, ys1 * xo, hi, lo);
        ((u32*)QRH)[u32b] = hi;
        ((u32*)QRL)[u32b] = lo;
      }
      __syncthreads();
    }
  }
}

// G4b: part[ks*4+h] = (xyh+xyl)[ks-half] @ dec_hi[h][ks-half].  2-term, double-buffered.
// grid(16,2,8): z = h + 4*ks.  per-b.
__global__ __launch_bounds__(256) void k_g4b(const u16* __restrict__ xyH,
                                             const u16* __restrict__ xyL,
                                             const u16* __restrict__ dtH,
                                             float* __restrict__ part) {
  GEMM_PRE2D
  int it = blockIdx.x, jt = blockIdx.y;
  int h = blockIdx.z & 3, ks = blockIdx.z >> 2;
  int t0 = it * 128;
  size_t ao = (size_t)(h * T_ + t0) * NN_;
  size_t bo = (size_t)h * D_ * NN_ + (size_t)jt * 128 * NN_;
  int k0 = ks * 32, k1 = ks * 32 + 32;
  {  // prologue
    stage_t(xyH + ao + k0 * 64, NN_, smd, wid, lane);
    stage_t(xyL + ao + k0 * 64, NN_, smd + 8192, wid, lane);
    stage_t(dtH + bo + k0 * 64, NN_, smd + 16384, wid, lane);
  }
  for (int kb = k0; kb < k1; ++kb) {
    short* cur = smd + ((kb - k0) & 1) * 24576;
    __syncthreads();
    if (kb + 1 < k1) {
      short* nxt = smd + ((kb + 1 - k0) & 1) * 24576;
      stage_t(xyH + ao + (kb + 1) * 64, NN_, nxt, wid, lane);
      stage_t(xyL + ao + (kb + 1) * 64, NN_, nxt + 8192, wid, lane);
      stage_t(dtH + bo + (kb + 1) * 64, NN_, nxt + 16384, wid, lane);
    }
    mma64x2(cur, cur + 8192, cur + 16384, wr, wc, lane, acc);
  }
  __syncthreads();
#pragma unroll
  for (int pass = 0; pass < 2; ++pass) {
    acc_store_half(bounce, acc, pass, wr, wc, lane, false);
    __syncthreads();
    for (int w = 0; w < 32; ++w) {
      int e = w * 256 + tid;
      int row = e >> 7, col = e & 127;
      part[((size_t)blockIdx.z * T_ + t0 + pass * 64 + row) * 256 + jt * 128 + col] =
          bounce[row * 128 + col];
    }
    __syncthreads();
  }
}

// LN3: yMLP = sum of 8 part slabs (f32); x = ln(x + ln(yMLP)); refresh x, xb hi/lo. 512 blocks.
__global__ __launch_bounds__(256) void k_ln3(const float* __restrict__ part, float* __restrict__ x,
                                             u16* __restrict__ xbH, u16* __restrict__ xbL) {
  int lane = threadIdx.x & 63, wid = threadIdx.x >> 6;
  int r = blockIdx.x * 4 + wid;
  float a0 = 0, a1 = 0, a2 = 0, a3 = 0;
#pragma unroll
  for (int h = 0; h < 8; ++h) {
    float4 u = ((const float4*)(part + ((size_t)h * T_ + r) * 256))[lane];
    a0 += u.x; a1 += u.y; a2 += u.z; a3 += u.w;
  }
  float m = wsum(a0 + a1 + a2 + a3) * (1.0f / 256.0f);
  float d0 = a0 - m, d1 = a1 - m, d2 = a2 - m, d3 = a3 - m;
  float var = wsum(d0 * d0 + d1 * d1 + d2 * d2 + d3 * d3) * (1.0f / 256.0f);
  float rs = 1.0f / sqrtf(var + 1e-5f);
  float4 xv = ((const float4*)(x + (size_t)r * 256))[lane];
  float s0 = xv.x + d0 * rs, s1 = xv.y + d1 * rs, s2 = xv.z + d2 * rs, s3 = xv.w + d3 * rs;
  float m2 = wsum(s0 + s1 + s2 + s3) * (1.0f / 256.0f);
  float e0 = s0 - m2, e1 = s1 - m2, e2 = s2 - m2, e3 = s3 - m2;
  float var2 = wsum(e0 * e0 + e1 * e1 + e2 * e2 + e3 * e3) * (1.0f / 256.0f);
  float rs2 = 1.0f / sqrtf(var2 + 1e-5f);
  float y0 = e0 * rs2, y1 = e1 * rs2, y2 = e2 * rs2, y3 = e3 * rs2;
  ((float4*)(x + (size_t)r * 256))[lane] = make_float4(y0, y1, y2, y3);
  ushort4 oh, ol;
  oh.x = f2b(y0); ol.x = f2b(y0 - b2f(oh.x));
  oh.y = f2b(y1); ol.y = f2b(y1 - b2f(oh.y));
  oh.z = f2b(y2); ol.z = f2b(y2 - b2f(oh.z));
  oh.w = f2b(y3); ol.w = f2b(y3 - b2f(oh.w));
  ((ushort4*)(xbH + (size_t)r * 256))[lane] = oh;
  ((ushort4*)(xbL + (size_t)r * 256))[lane] = ol;
}

// G5: logits = xb @ lm_head (3-term) -> f32 out (rows offset by b).  grid(16,2), per-b.
__global__ __launch_bounds__(256) void k_g5(const u16* __restrict__ xbH,
                                            const u16* __restrict__ xbL,
                                            const u16* __restrict__ lmH,
                                            const u16* __restrict__ lmL,
                                            float* __restrict__ out) {
  __shared__ float smf[16384];
  short* AsH = (short*)smf;
  short* AsL = AsH + 8192;
  short* BsH = AsH + 16384;
  short* BsL = AsH + 24576;
  int tid = threadIdx.x;
  int lane = tid & 63, wid = tid >> 6;
  int wr = wid >> 1, wc = wid & 1;
  f4 acc[4][4];
  acc_zero(acc);
  int it = blockIdx.x, jt = blockIdx.y;
  size_t ao = (size_t)it * 128 * 256;
  size_t bo = (size_t)jt * 128 * 256;
  for (int kb = 0; kb < 4; ++kb) {
    stage_t(xbH + ao + kb * 64, 256, AsH, wid, lane);
    stage_t(xbL + ao + kb * 64, 256, AsL, wid, lane);
    stage_t(lmH + bo + kb * 64, 256, BsH, wid, lane);
    stage_t(lmL + bo + kb * 64, 256, BsL, wid, lane);
    __syncthreads();
    mma64x3(AsH, AsL, BsH, BsL, wr, wc, lane, acc);
    __syncthreads();
  }
  acc_store_f32(smf, acc, wr, wc, lane, false);
  __syncthreads();
  for (int w = 0; w < 64; ++w) {
    int e = w * 256 + tid;
    int row = e >> 7, col = e & 127;
    out[(size_t)(it * 128 + row) * 256 + jt * 128 + col] = smf[row * 128 + col];
  }
}

extern "C" void kernel_launch(void* const* d_in, const int* in_sizes, int n_in, void* d_out,
                              int out_size, void* d_ws, size_t ws_size, hipStream_t stream) {
  const int*   idx   = (const int*)d_in[0];
  const float* embed = (const float*)d_in[1];
  const float* enc   = (const float*)d_in[2];
  const float* encv  = (const float*)d_in[3];
  const float* dec   = (const float*)d_in[4];
  const float* lm    = (const float*)d_in[5];

  if (ws_size < WS_NEED) {  // sentinel: undersized workspace is diagnosable (bf16-trunc 12672 pattern)
    hipMemsetAsync(d_out, 0x46, (size_t)out_size * 4, stream);
    return;
  }

  char* w = (char*)d_ws;
  float2* csA  = (float2*)(w + CSA_OFF);
  float2* csB  = (float2*)(w + CSB_OFF);
  u16*    etH  = (u16*)(w + ETH_OFF);
  u16*    etL  = (u16*)(w + ETL_OFF);
  u16*    evH  = (u16*)(w + EVH_OFF);
  u16*    evL  = (u16*)(w + EVL_OFF);
  u16*    dtH  = (u16*)(w + DTH_OFF);
  u16*    dtL  = (u16*)(w + DTL_OFF);
  u16*    lmH  = (u16*)(w + LMH_OFF);
  u16*    lmL  = (u16*)(w + LML_OFF);
  float*  x    = (float*)(w + X_OFF);
  u16*    xbH  = (u16*)(w + XBH_OFF);
  u16*    xbL  = (u16*)(w + XBL_OFF);
  u16*    xbTH = (u16*)(w + XBTH_OFF);
  u16*    xbTL = (u16*)(w + XBTL_OFF);
  u16*    QRH  = (u16*)(w + QRH_OFF);
  u16*    QRL  = (u16*)(w + QRL_OFF);
  u16*    SpH  = (u16*)(w + SH_OFF);
  float*  part = (float*)(w + SH_OFF);   // overlays S-hi (S dead after G3); 16MB < 17.8MB
  float*  yKV1 = (float*)(w + SL_OFF);   // freed S-lo region -> g3 partial 1
  float*  yKV0 = (float*)(w + YKV_OFF);
  u16*    ykH  = (u16*)(w + YKBH_OFF);
  u16*    ykL  = (u16*)(w + YKBL_OFF);

  k_costab<<<1152, 256, 0, stream>>>(csA, csB);
  k_tcast2<<<dim3(128, 8, 4), dim3(32, 8), 0, stream>>>(enc, etH, etL, 256, 4096);
  k_tcast2<<<dim3(128, 8, 4), dim3(32, 8), 0, stream>>>(encv, evH, evL, 256, 4096);
  k_tcast2<<<dim3(8, 128, 4), dim3(32, 8), 0, stream>>>(dec, dtH, dtL, 4096, 256);
  k_tcast2<<<dim3(8, 8, 1), dim3(32, 8), 0, stream>>>(lm, lmH, lmL, 256, 256);

  for (int b = 0; b < 2; ++b) {
    k_ln_embed<<<512, 256, 0, stream>>>(idx, embed, b, x, xbH, xbL);
    k_xbt<<<2048, 256, 0, stream>>>(xbH, xbL, xbTH, xbTL);
    for (int l = 0; l < NLAYER; ++l) {
      k_g1<<<dim3(16, 11, 4), 256, 0, stream>>>(xbH, xbL, etH, csA, csB, QRH, QRL);
      k_g2<<<204, 256, 0, stream>>>(QRH, QRL, SpH);
      k_g3<<<dim3(16, 2, 8), 256, 0, stream>>>(SpH, xbTH, xbTL, yKV0, yKV1);
      k_ln_f32<<<2048, 256, 0, stream>>>(yKV0, yKV1, ykH, ykL);
      k_g4a<<<dim3(16, 11, 4), 256, 0, stream>>>(ykH, ykL, evH, csA, csB, QRH, QRL);
      k_g4b<<<dim3(16, 2, 8), 256, 0, stream>>>(QRH, QRL, dtH, part);
      k_ln3<<<512, 256, 0, stream>>>(part, x, xbH, xbL);
      k_xbt<<<2048, 256, 0, stream>>>(xbH, xbL, xbTH, xbTL);
    }
    k_g5<<<dim3(16, 2), 256, 0, stream>>>(xbH, xbL, lmH, lmL, (float*)d_out + (size_t)b * T_ * 256);
  }
}

// Round 15
// 4617.195 us; speedup vs baseline: 1.2050x; 1.2050x over previous
//
#include <hip/hip_runtime.h>

// ===== BDH forward on MI355X — R15: R13 revert + g2 full double-buffer @160KB =====
// R14 regressed (g1/g4a lost block-parallelism; A-hoist neutral on g2). R15 =
// R13 exactly (4687us), except k_g2: 2x80KB double-buffered row-triple (g2 is
// already 1 blk/CU, so dbuf costs no occupancy — R12 lesson applied correctly).
// Fused A-hoist mma_a2b3 inside. Bit-identical math.

typedef unsigned short u16;
typedef unsigned int   u32;
typedef __attribute__((ext_vector_type(8))) short bf8;
typedef __attribute__((ext_vector_type(4))) float f4;

#define T_  2048
#define D_  256
#define NH_ 4
#define NN_ 4096
#define NLAYER 6

// ---- workspace layout (bytes); per-b activation buffers ----
#define CSA_OFF  ((size_t)0)                    // float2 [16][2048]  coarse-t trig
#define CSB_OFF  (CSA_OFF  + 262144)            // float2 [128][2048] fine-t trig
#define ETH_OFF  (CSB_OFF  + 2097152)           // bf16 [4][4096][256] enc^T hi
#define ETL_OFF  (ETH_OFF  + 8388608)
#define EVH_OFF  (ETL_OFF  + 8388608)
#define EVL_OFF  (EVH_OFF  + 8388608)
#define DTH_OFF  (EVL_OFF  + 8388608)           // bf16 [4][256][4096] dec^T hi
#define DTL_OFF  (DTH_OFF  + 8388608)
#define LMH_OFF  (DTL_OFF  + 8388608)           // bf16 [256][256] lm^T
#define LML_OFF  (LMH_OFF  + 131072)
#define X_OFF    (LML_OFF  + 131072)            // f32  [2048][256] x (per-b)
#define XBH_OFF  (X_OFF    + 2097152)           // bf16 [2048][256] (per-b)
#define XBL_OFF  (XBH_OFF  + 1048576)
#define XBTH_OFF (XBL_OFF  + 1048576)           // bf16 [256][2048] (per-b)
#define XBTL_OFF (XBTH_OFF + 1048576)
#define QRH_OFF  (XBTL_OFF + 1048576)           // bf16 [4][2048][4096] QR/xy hi (per-b)
#define QRL_OFF  (QRH_OFF  + 67108864)
#define SH_OFF   (QRL_OFF  + 67108864)          // bf16 [4][136][16384] S hi (per-b); part f32 overlays
#define SL_OFF   (SH_OFF   + 17825792)          // FREED (no S-lo) -> f32 yKV partial-1
#define YKV_OFF  (SL_OFF   + 17825792)          // f32  [4][2048][256] yKV partial-0 (per-b)
#define YKBH_OFF (YKV_OFF  + 8388608)           // bf16 ln(yKV) hi (per-b)
#define YKBL_OFF (YKBH_OFF + 4194304)
#define IDX_END  (YKBL_OFF + 4194304)
#define WS_NEED  (IDX_END  + 16384)             // = 245,907,456 < 253,902,848 proven

// ---------- helpers ----------
__device__ __forceinline__ u16 f2b(float f) {               // RTNE f32->bf16
  u32 u = __builtin_bit_cast(u32, f);
  u32 r = u + 0x7fffu + ((u >> 16) & 1u);
  return (u16)(r >> 16);
}
__device__ __forceinline__ float b2f(u16 h) {
  u32 u = ((u32)h) << 16;
  return __builtin_bit_cast(float, u);
}
__device__ __forceinline__ void split2(float q0, float q1, u32& hi, u32& lo) {
  u16 h0 = f2b(q0), h1 = f2b(q1);
  u16 l0 = f2b(q0 - b2f(h0)), l1 = f2b(q1 - b2f(h1));
  hi = (u32)h0 | ((u32)h1 << 16);
  lo = (u32)l0 | ((u32)l1 << 16);
}
__device__ __forceinline__ float wsum(float v) {
#pragma unroll
  for (int o = 32; o; o >>= 1) v += __shfl_xor(v, o, 64);
  return v;
}
// trig from factored tables: pp = pair index [0,2048), t = time [0,2048)
__device__ __forceinline__ float2 trig_ct(const float2* csA, const float2* csB, int t, int pp) {
  float2 a = csA[(t >> 7) * 2048 + pp];
  float2 b = csB[(t & 127) * 2048 + pp];
  return make_float2(a.x * b.x - a.y * b.y, a.x * b.y + a.y * b.x);
}
__device__ __forceinline__ void gld16(const u16* g, short* l) {
  __builtin_amdgcn_global_load_lds(
      (const __attribute__((address_space(1))) u32*)g,
      (__attribute__((address_space(3))) u32*)l, 16, 0, 0);
}
// stage 128x64 bf16 tile into LDS [128][64], XOR-swizzled (T2, both-sides):
// linear LDS dest (global_load_lds req) + pre-swizzled global source col.
__device__ __forceinline__ void stage_t(const u16* g, int lda, short* s, int wid, int lane) {
  int r8 = lane >> 3;                       // 0..7 rows within 8-row stripe
  int c8 = ((lane & 7) ^ r8) * 8;           // pre-swizzled source column slot
#pragma unroll
  for (int j = 0; j < 4; ++j) {
    int row = wid * 32 + j * 8;             // multiple of 8 -> (row+r8)&7 == r8
    gld16(g + (size_t)(row + r8) * lda + c8, s + row * 64);
  }
}
// BK=64 step, 3-term split: 96 MFMA (hh, lh, hl) — g5 only
__device__ __forceinline__ void mma64x3(const short* AsH, const short* AsL, const short* BsH,
                                        const short* BsL, int wr, int wc, int lane,
                                        f4 acc[4][4]) {
  int r15 = lane & 15, hi = lane >> 4;
  int sw = (r15 & 7) << 3;
#pragma unroll
  for (int kk = 0; kk < 2; ++kk) {
    int ko = (kk * 32 + hi * 8) ^ sw;
    bf8 ah[4], al[4], bh[4], bl[4];
#pragma unroll
    for (int m = 0; m < 4; ++m) {
      int off = (wr * 64 + m * 16 + r15) * 64 + ko;
      ah[m] = *(const bf8*)(AsH + off);
      al[m] = *(const bf8*)(AsL + off);
    }
#pragma unroll
    for (int n = 0; n < 4; ++n) {
      int off = (wc * 64 + n * 16 + r15) * 64 + ko;
      bh[n] = *(const bf8*)(BsH + off);
      bl[n] = *(const bf8*)(BsL + off);
    }
#pragma unroll
    for (int m = 0; m < 4; ++m)
#pragma unroll
      for (int n = 0; n < 4; ++n) {
        acc[m][n] = __builtin_amdgcn_mfma_f32_16x16x32_bf16(ah[m], bh[n], acc[m][n], 0, 0, 0);
        acc[m][n] = __builtin_amdgcn_mfma_f32_16x16x32_bf16(al[m], bh[n], acc[m][n], 0, 0, 0);
        acc[m][n] = __builtin_amdgcn_mfma_f32_16x16x32_bf16(ah[m], bl[n], acc[m][n], 0, 0, 0);
      }
  }
}
// BK=64 step, 2-term A-split: acc += (Ah+Al)*Bh^T  (64 MFMA) — g1/g4a/g4b
__device__ __forceinline__ void mma64x2(const short* AsH, const short* AsL, const short* BsH,
                                        int wr, int wc, int lane, f4 acc[4][4]) {
  int r15 = lane & 15, hi = lane >> 4;
  int sw = (r15 & 7) << 3;
#pragma unroll
  for (int kk = 0; kk < 2; ++kk) {
    int ko = (kk * 32 + hi * 8) ^ sw;
    bf8 ah[4], al[4], bh[4];
#pragma unroll
    for (int m = 0; m < 4; ++m) {
      int off = (wr * 64 + m * 16 + r15) * 64 + ko;
      ah[m] = *(const bf8*)(AsH + off);
      al[m] = *(const bf8*)(AsL + off);
    }
#pragma unroll
    for (int n = 0; n < 4; ++n)
      bh[n] = *(const bf8*)(BsH + (wc * 64 + n * 16 + r15) * 64 + ko);
#pragma unroll
    for (int m = 0; m < 4; ++m)
#pragma unroll
      for (int n = 0; n < 4; ++n) {
        acc[m][n] = __builtin_amdgcn_mfma_f32_16x16x32_bf16(ah[m], bh[n], acc[m][n], 0, 0, 0);
        acc[m][n] = __builtin_amdgcn_mfma_f32_16x16x32_bf16(al[m], bh[n], acc[m][n], 0, 0, 0);
      }
  }
}
// BK=64 step, fused 2-term x 3 B-panels: A-frags read once per kk — g2
__device__ __forceinline__ void mma_a2b3(const short* AsH, const short* AsL, const short* B0,
                                         const short* B1, const short* B2, bool has1, bool has2,
                                         int wr, int wc, int lane, f4 acc0[4][4], f4 acc1[4][4],
                                         f4 acc2[4][4]) {
  int r15 = lane & 15, hi = lane >> 4;
  int sw = (r15 & 7) << 3;
#pragma unroll
  for (int kk = 0; kk < 2; ++kk) {
    int ko = (kk * 32 + hi * 8) ^ sw;
    bf8 ah[4], al[4], bh[4];
#pragma unroll
    for (int m = 0; m < 4; ++m) {
      int off = (wr * 64 + m * 16 + r15) * 64 + ko;
      ah[m] = *(const bf8*)(AsH + off);
      al[m] = *(const bf8*)(AsL + off);
    }
#pragma unroll
    for (int n = 0; n < 4; ++n) bh[n] = *(const bf8*)(B0 + (wc * 64 + n * 16 + r15) * 64 + ko);
#pragma unroll
    for (int m = 0; m < 4; ++m)
#pragma unroll
      for (int n = 0; n < 4; ++n) {
        acc0[m][n] = __builtin_amdgcn_mfma_f32_16x16x32_bf16(ah[m], bh[n], acc0[m][n], 0, 0, 0);
        acc0[m][n] = __builtin_amdgcn_mfma_f32_16x16x32_bf16(al[m], bh[n], acc0[m][n], 0, 0, 0);
      }
    if (has1) {
#pragma unroll
      for (int n = 0; n < 4; ++n) bh[n] = *(const bf8*)(B1 + (wc * 64 + n * 16 + r15) * 64 + ko);
#pragma unroll
      for (int m = 0; m < 4; ++m)
#pragma unroll
        for (int n = 0; n < 4; ++n) {
          acc1[m][n] = __builtin_amdgcn_mfma_f32_16x16x32_bf16(ah[m], bh[n], acc1[m][n], 0, 0, 0);
          acc1[m][n] = __builtin_amdgcn_mfma_f32_16x16x32_bf16(al[m], bh[n], acc1[m][n], 0, 0, 0);
        }
    }
    if (has2) {
#pragma unroll
      for (int n = 0; n < 4; ++n) bh[n] = *(const bf8*)(B2 + (wc * 64 + n * 16 + r15) * 64 + ko);
#pragma unroll
      for (int m = 0; m < 4; ++m)
#pragma unroll
        for (int n = 0; n < 4; ++n) {
          acc2[m][n] = __builtin_amdgcn_mfma_f32_16x16x32_bf16(ah[m], bh[n], acc2[m][n], 0, 0, 0);
          acc2[m][n] = __builtin_amdgcn_mfma_f32_16x16x32_bf16(al[m], bh[n], acc2[m][n], 0, 0, 0);
        }
    }
  }
}
// BK=64 step, 2-term B-split: acc += Ah*(Bh+Bl)^T  (64 MFMA) — g3
__device__ __forceinline__ void mma64x2b(const short* AsH, const short* BsH, const short* BsL,
                                         int wr, int wc, int lane, f4 acc[4][4]) {
  int r15 = lane & 15, hi = lane >> 4;
  int sw = (r15 & 7) << 3;
#pragma unroll
  for (int kk = 0; kk < 2; ++kk) {
    int ko = (kk * 32 + hi * 8) ^ sw;
    bf8 ah[4], bh[4], bl[4];
#pragma unroll
    for (int m = 0; m < 4; ++m)
      ah[m] = *(const bf8*)(AsH + (wr * 64 + m * 16 + r15) * 64 + ko);
#pragma unroll
    for (int n = 0; n < 4; ++n) {
      int off = (wc * 64 + n * 16 + r15) * 64 + ko;
      bh[n] = *(const bf8*)(BsH + off);
      bl[n] = *(const bf8*)(BsL + off);
    }
#pragma unroll
    for (int m = 0; m < 4; ++m)
#pragma unroll
      for (int n = 0; n < 4; ++n) {
        acc[m][n] = __builtin_amdgcn_mfma_f32_16x16x32_bf16(ah[m], bh[n], acc[m][n], 0, 0, 0);
        acc[m][n] = __builtin_amdgcn_mfma_f32_16x16x32_bf16(ah[m], bl[n], acc[m][n], 0, 0, 0);
      }
  }
}
__device__ __forceinline__ void acc_zero(f4 acc[4][4]) {
#pragma unroll
  for (int m = 0; m < 4; ++m)
#pragma unroll
    for (int n = 0; n < 4; ++n)
#pragma unroll
      for (int j = 0; j < 4; ++j) acc[m][n][j] = 0.0f;
}
// C frag (col=lane&15, row=(lane>>4)*4+j) -> f32 LDS bounce [128][128] (g5)
__device__ __forceinline__ void acc_store_f32(float* F, f4 acc[4][4], int wr, int wc, int lane,
                                              bool relu) {
  int r15 = lane & 15, q = lane >> 4;
#pragma unroll
  for (int m = 0; m < 4; ++m)
#pragma unroll
    for (int n = 0; n < 4; ++n)
#pragma unroll
      for (int j = 0; j < 4; ++j) {
        float v = acc[m][n][j];
        if (relu) v = fmaxf(v, 0.0f);
        F[(wr * 64 + m * 16 + q * 4 + j) * 128 + wc * 64 + n * 16 + r15] = v;
      }
}
// half-store (pass p writes waves wr==p) into [64][128] f32 bounce (32KB)
__device__ __forceinline__ void acc_store_half(float* F, f4 acc[4][4], int pass, int wr, int wc,
                                               int lane, bool relu) {
  if (wr != pass) return;
  int r15 = lane & 15, q = lane >> 4;
#pragma unroll
  for (int m = 0; m < 4; ++m)
#pragma unroll
    for (int n = 0; n < 4; ++n)
#pragma unroll
      for (int j = 0; j < 4; ++j) {
        float v = acc[m][n][j];
        if (relu) v = fmaxf(v, 0.0f);
        F[(m * 16 + q * 4 + j) * 128 + wc * 64 + n * 16 + r15] = v;
      }
}

// ---------- prep kernels ----------
// factored trig tables, f64-built. 144 rows x 2048 pairs.
__global__ __launch_bounds__(256) void k_costab(float2* csA, float2* csB) {
  int id = blockIdx.x * 256 + threadIdx.x;  // 1152 blocks -> 294912
  int r = id >> 11, p = id & 2047;
  double freq = exp2(-(double)p / 128.0) * 0.15915494309189533577;  // theta=2^16, incl 1/(2pi)
  int t = (r < 16) ? (r * 128) : (r - 16);
  double ph = fmod((double)t * freq, 1.0);
  double ang = ph * 6.2831853071795864769;
  float2 v = make_float2((float)cos(ang), (float)sin(ang));
  if (r < 16) csA[r * 2048 + p] = v;
  else        csB[(r - 16) * 2048 + p] = v;
}

// transpose+cast to hi/lo: in f32 (R,C) -> out bf16 (C,R) x2
__global__ __launch_bounds__(256) void k_tcast2(const float* __restrict__ in,
                                                u16* __restrict__ outH, u16* __restrict__ outL,
                                                int R, int C) {
  __shared__ float tl[32][33];
  size_t bo = (size_t)blockIdx.z * R * C;
  int tx = threadIdx.x, ty = threadIdx.y;
  int c = blockIdx.x * 32 + tx, r0 = blockIdx.y * 32 + ty;
#pragma unroll
  for (int k = 0; k < 32; k += 8) tl[ty + k][tx] = in[bo + (size_t)(r0 + k) * C + c];
  __syncthreads();
  int rr = blockIdx.y * 32 + tx, cc0 = blockIdx.x * 32 + ty;
#pragma unroll
  for (int k = 0; k < 32; k += 8) {
    float v = tl[tx][ty + k];
    u16 h = f2b(v);
    outH[bo + (size_t)(cc0 + k) * R + rr] = h;
    outL[bo + (size_t)(cc0 + k) * R + rr] = f2b(v - b2f(h));
  }
}

// ln(embed[idx]) for batch b -> x (f32, per-b), xb hi/lo (per-b). 512 blocks.
__global__ __launch_bounds__(256) void k_ln_embed(const int* __restrict__ idx,
                                                  const float* __restrict__ embed, int b,
                                                  float* __restrict__ x, u16* __restrict__ xbH,
                                                  u16* __restrict__ xbL) {
  int lane = threadIdx.x & 63, wid = threadIdx.x >> 6;
  int r = blockIdx.x * 4 + wid;                 // [0,2048)
  int id = idx[b * T_ + r] & 255;
  float4 v = ((const float4*)(embed + (size_t)id * 256))[lane];
  float m = wsum(v.x + v.y + v.z + v.w) * (1.0f / 256.0f);
  float d0 = v.x - m, d1 = v.y - m, d2 = v.z - m, d3 = v.w - m;
  float var = wsum(d0 * d0 + d1 * d1 + d2 * d2 + d3 * d3) * (1.0f / 256.0f);
  float rs = 1.0f / sqrtf(var + 1e-5f);
  float y0 = d0 * rs, y1 = d1 * rs, y2 = d2 * rs, y3 = d3 * rs;
  ((float4*)(x + (size_t)r * 256))[lane] = make_float4(y0, y1, y2, y3);
  ushort4 oh, ol;
  oh.x = f2b(y0); ol.x = f2b(y0 - b2f(oh.x));
  oh.y = f2b(y1); ol.y = f2b(y1 - b2f(oh.y));
  oh.z = f2b(y2); ol.z = f2b(y2 - b2f(oh.z));
  oh.w = f2b(y3); ol.w = f2b(y3 - b2f(oh.w));
  ((ushort4*)(xbH + (size_t)r * 256))[lane] = oh;
  ((ushort4*)(xbL + (size_t)r * 256))[lane] = ol;
}

// per-b transpose xb -> xbT ([256][2048]). 2048 blocks.
__global__ __launch_bounds__(256) void k_xbt(const u16* __restrict__ xbH,
                                             const u16* __restrict__ xbL,
                                             u16* __restrict__ xbTH, u16* __restrict__ xbTL) {
  int id = blockIdx.x * 256 + threadIdx.x;      // 256*2048
  int t = id & 2047, d = id >> 11;
  size_t src = (size_t)t * 256 + d;
  xbTH[id] = xbH[src];
  xbTL[id] = xbL[src];
}

// ---------- GEMM kernels ----------
// 48KB single-buffer preamble (g1/g4a)
#define GEMM_PRE2                                                       \
  __shared__ short sm2[24576];                                          \
  short* T0 = sm2;                                                      \
  short* T1 = sm2 + 8192;                                               \
  short* T2 = sm2 + 16384;                                              \
  float* bounce = (float*)sm2;                                          \
  int tid = threadIdx.x;                                                \
  int lane = tid & 63, wid = tid >> 6;                                  \
  int wr = wid >> 1, wc = wid & 1;                                      \
  f4 acc[4][4];                                                         \
  acc_zero(acc);

// 96KB double-buffer preamble (g3/g4b)
#define GEMM_PRE2D                                                      \
  __shared__ short smd[49152];                                          \
  float* bounce = (float*)smd;                                          \
  int tid = threadIdx.x;                                                \
  int lane = tid & 63, wid = tid >> 6;                                  \
  int wr = wid >> 1, wc = wid & 1;                                      \
  f4 acc[4][4];                                                         \
  acc_zero(acc);

// G1: x_sparse=relu(xb@enc_hi[h]) -> rope -> QR hi/lo.  2-term. grid(16,32,4), per-b.
__global__ __launch_bounds__(256) void k_g1(const u16* __restrict__ xbH, const u16* __restrict__ xbL,
                                            const u16* __restrict__ etH,
                                            const float2* __restrict__ csA,
                                            const float2* __restrict__ csB,
                                            u16* __restrict__ QRH, u16* __restrict__ QRL) {
  GEMM_PRE2
  int it = blockIdx.x, jt = blockIdx.y, h = blockIdx.z;
  size_t ao = (size_t)it * 128 * 256;
  size_t bo = (size_t)h * NN_ * 256 + (size_t)jt * 128 * 256;
  for (int kb = 0; kb < 4; ++kb) {
    stage_t(xbH + ao + kb * 64, 256, T0, wid, lane);
    stage_t(xbL + ao + kb * 64, 256, T1, wid, lane);
    stage_t(etH + bo + kb * 64, 256, T2, wid, lane);
    __syncthreads();
    mma64x2(T0, T1, T2, wr, wc, lane, acc);
    __syncthreads();
  }
#pragma unroll
  for (int pass = 0; pass < 2; ++pass) {
    acc_store_half(bounce, acc, pass, wr, wc, lane, true);  // relu(x_latent)
    __syncthreads();
    for (int w = 0; w < 16; ++w) {
      int e = w * 256 + tid;                 // 4096 pairs
      int rrel = e >> 6, p = e & 63;
      float v0 = bounce[rrel * 128 + 2 * p], v1 = bounce[rrel * 128 + 2 * p + 1];
      int t = it * 128 + pass * 64 + rrel, pp = jt * 64 + p;
      float2 c = trig_ct(csA, csB, t, pp);
      float q0 = v0 * c.x - v1 * c.y;
      float q1 = v1 * c.x + v0 * c.y;
      u32 hi, lo;
      split2(q0, q1, hi, lo);
      size_t u32b = (size_t)(h * T_ + t) * 2048 + pp;
      ((u32*)QRH)[u32b] = hi;
      ((u32*)QRL)[u32b] = lo;
    }
    __syncthreads();
  }
}

// G2: S = mask((Qh+Ql)@Qh^T), lower-tri, row-triple blocks, FULL double-buffer.
// 1D grid 204 per b (4h x 51 groups), bijective XCD chunk.  160KB LDS (2x80KB).
__global__ __launch_bounds__(256) void k_g2(const u16* __restrict__ QRH,
                                            const u16* __restrict__ QRL,
                                            u16* __restrict__ SpH) {
  __shared__ short smp[81920];             // 160KB: 2 x (AsH|AsL|B0|B1|B2)
  float* bounce = (float*)smp;             // first 32KB as [64][128] f32 (epilogue)
  int tid = threadIdx.x;
  int lane = tid & 63, wid = tid >> 6;
  int wr = wid >> 1, wc = wid & 1;
  f4 acc0[4][4], acc1[4][4], acc2[4][4];
  acc_zero(acc0); acc_zero(acc1); acc_zero(acc2);
  // bijective XCD chunking for N=204: q=25, r=4 (m204)
  int orig = blockIdx.x;
  int xcd = orig & 7, sub = orig >> 3;
  int lb = (xcd < 4 ? xcd * 26 : 104 + (xcd - 4) * 25) + sub;
  int h = lb / 51;
  int rem = lb % 51, i = 0;
  while (rem >= (i + 3) / 3) { rem -= (i + 3) / 3; ++i; }
  int j0 = rem * 3, j1 = j0 + 1, j2 = j0 + 2;
  bool has1 = (j1 <= i), has2 = (j2 <= i);
  size_t base = (size_t)h * T_ * NN_;
  size_t ao = base + (size_t)i * 128 * NN_;
  size_t bo0 = base + (size_t)j0 * 128 * NN_;
  size_t bo1 = base + (size_t)j1 * 128 * NN_;
  size_t bo2 = base + (size_t)j2 * 128 * NN_;
  {  // prologue: stage k=0 into buf0
    stage_t(QRH + ao, NN_, smp, wid, lane);
    stage_t(QRL + ao, NN_, smp + 8192, wid, lane);
    stage_t(QRH + bo0, NN_, smp + 16384, wid, lane);
    if (has1) stage_t(QRH + bo1, NN_, smp + 24576, wid, lane);
    if (has2) stage_t(QRH + bo2, NN_, smp + 32768, wid, lane);
  }
  for (int kb = 0; kb < 64; ++kb) {
    short* cur = smp + (kb & 1) * 40960;
    __syncthreads();                 // drains cur's loads (issued 1 phase ago); prev readers done
    if (kb + 1 < 64) {
      short* nxt = smp + ((kb + 1) & 1) * 40960;
      stage_t(QRH + ao + (kb + 1) * 64, NN_, nxt, wid, lane);
      stage_t(QRL + ao + (kb + 1) * 64, NN_, nxt + 8192, wid, lane);
      stage_t(QRH + bo0 + (kb + 1) * 64, NN_, nxt + 16384, wid, lane);
      if (has1) stage_t(QRH + bo1 + (kb + 1) * 64, NN_, nxt + 24576, wid, lane);
      if (has2) stage_t(QRH + bo2 + (kb + 1) * 64, NN_, nxt + 32768, wid, lane);
    }
    mma_a2b3(cur, cur + 8192, cur + 16384, cur + 24576, cur + 32768, has1, has2, wr, wc, lane,
             acc0, acc1, acc2);
  }
  __syncthreads();
  // epilogue: up to 3 output blocks, 2-pass bounce each
#pragma unroll
  for (int jb = 0; jb < 3; ++jb) {
    if (jb == 1 && !has1) break;
    if (jb == 2 && !has2) break;
    int j = j0 + jb;
    size_t dblk = ((size_t)h * 136 + (size_t)i * (i + 1) / 2 + j) * 16384;
    bool diag = (i == j);
#pragma unroll
    for (int pass = 0; pass < 2; ++pass) {
      if (jb == 0) acc_store_half(bounce, acc0, pass, wr, wc, lane, false);
      else if (jb == 1) acc_store_half(bounce, acc1, pass, wr, wc, lane, false);
      else acc_store_half(bounce, acc2, pass, wr, wc, lane, false);
      __syncthreads();
      for (int w = 0; w < 16; ++w) {
        int e = w * 256 + tid;
        int rrel = e >> 6, p = e & 63;
        int row = pass * 64 + rrel;
        float s0 = bounce[rrel * 128 + 2 * p], s1 = bounce[rrel * 128 + 2 * p + 1];
        if (diag) {  // strictly lower: col < row
          if (2 * p >= row) s0 = 0.0f;
          if (2 * p + 1 >= row) s1 = 0.0f;
        }
        u32 hi = (u32)f2b(s0) | ((u32)f2b(s1) << 16);
        ((u32*)SpH)[(dblk >> 1) + row * 64 + p] = hi;
      }
      __syncthreads();
    }
  }
}

// G3: yKV_partial = S_hi @ (xh+xl), split-K x2, double-buffered.
// grid(16,2,8): z = h + 4*ks.  per-b.
__global__ __launch_bounds__(256) void k_g3(const u16* __restrict__ SpH,
                                            const u16* __restrict__ xbTH,
                                            const u16* __restrict__ xbTL,
                                            float* __restrict__ yKV0,
                                            float* __restrict__ yKV1) {
  GEMM_PRE2D
  int i = blockIdx.x, jt = blockIdx.y;
  int h = blockIdx.z & 3, ks = blockIdx.z >> 2;
  size_t tri = (size_t)h * 136 + (size_t)i * (i + 1) / 2;
  size_t bo = (size_t)jt * 128 * T_;
  int k0 = ks * (i + 1), k1 = (ks + 1) * (i + 1);   // half-step range
  {  // prologue
    size_t aoff = (tri + (k0 >> 1)) * 16384 + (k0 & 1) * 64;
    stage_t(SpH + aoff, 128, smd, wid, lane);
    stage_t(xbTH + bo + k0 * 64, T_, smd + 8192, wid, lane);
    stage_t(xbTL + bo + k0 * 64, T_, smd + 16384, wid, lane);
  }
  for (int kb = k0; kb < k1; ++kb) {
    short* cur = smd + ((kb - k0) & 1) * 24576;
    __syncthreads();
    if (kb + 1 < k1) {
      short* nxt = smd + ((kb + 1 - k0) & 1) * 24576;
      size_t aoff = (tri + ((kb + 1) >> 1)) * 16384 + ((kb + 1) & 1) * 64;
      stage_t(SpH + aoff, 128, nxt, wid, lane);
      stage_t(xbTH + bo + (kb + 1) * 64, T_, nxt + 8192, wid, lane);
      stage_t(xbTL + bo + (kb + 1) * 64, T_, nxt + 16384, wid, lane);
    }
    mma64x2b(cur, cur + 8192, cur + 16384, wr, wc, lane, acc);
  }
  __syncthreads();
  float* yout = ks ? yKV1 : yKV0;
#pragma unroll
  for (int pass = 0; pass < 2; ++pass) {
    acc_store_half(bounce, acc, pass, wr, wc, lane, false);
    __syncthreads();
    for (int w = 0; w < 32; ++w) {
      int e = w * 256 + tid;                 // 8192 elems
      int row = e >> 7, col = e & 127;
      yout[((size_t)h * T_ + i * 128 + pass * 64 + row) * 256 + jt * 128 + col] =
          bounce[row * 128 + col];
    }
    __syncthreads();
  }
}

// LN over f32 rows of 256 (sum of 2 partials) -> hi/lo bf16.  2048 blocks, per-b.
__global__ __launch_bounds__(256) void k_ln_f32(const float* __restrict__ in0,
                                                const float* __restrict__ in1,
                                                u16* __restrict__ outH, u16* __restrict__ outL) {
  int lane = threadIdx.x & 63, wid = threadIdx.x >> 6;
  int r = blockIdx.x * 4 + wid;
  float4 a = ((const float4*)(in0 + (size_t)r * 256))[lane];
  float4 b = ((const float4*)(in1 + (size_t)r * 256))[lane];
  float v0 = a.x + b.x, v1 = a.y + b.y, v2 = a.z + b.z, v3 = a.w + b.w;
  float m = wsum(v0 + v1 + v2 + v3) * (1.0f / 256.0f);
  float d0 = v0 - m, d1 = v1 - m, d2 = v2 - m, d3 = v3 - m;
  float var = wsum(d0 * d0 + d1 * d1 + d2 * d2 + d3 * d3) * (1.0f / 256.0f);
  float rs = 1.0f / sqrtf(var + 1e-5f);
  float y0 = d0 * rs, y1 = d1 * rs, y2 = d2 * rs, y3 = d3 * rs;
  ushort4 oh, ol;
  oh.x = f2b(y0); ol.x = f2b(y0 - b2f(oh.x));
  oh.y = f2b(y1); ol.y = f2b(y1 - b2f(oh.y));
  oh.z = f2b(y2); ol.z = f2b(y2 - b2f(oh.z));
  oh.w = f2b(y3); ol.w = f2b(y3 - b2f(oh.w));
  ((ushort4*)(outH + (size_t)r * 256))[lane] = oh;
  ((ushort4*)(outL + (size_t)r * 256))[lane] = ol;
}

// G4a: y_sparse=relu((ykh+ykl)@encv_hi[h]); gate by invrope(QR h+l); xy -> QR hi/lo.
// 2-term. grid(16,32,4), per-b.
__global__ __launch_bounds__(256) void k_g4a(const u16* __restrict__ ykH,
                                             const u16* __restrict__ ykL,
                                             const u16* __restrict__ evH,
                                             const float2* __restrict__ csA,
                                             const float2* __restrict__ csB,
                                             u16* __restrict__ QRH, u16* __restrict__ QRL) {
  GEMM_PRE2
  int it = blockIdx.x, jt = blockIdx.y, h = blockIdx.z;
  int t0 = it * 128;
  size_t ao = (size_t)(h * T_ + t0) * 256;
  size_t bo = (size_t)h * NN_ * 256 + (size_t)jt * 128 * 256;
  for (int kb = 0; kb < 4; ++kb) {
    stage_t(ykH + ao + kb * 64, 256, T0, wid, lane);
    stage_t(ykL + ao + kb * 64, 256, T1, wid, lane);
    stage_t(evH + bo + kb * 64, 256, T2, wid, lane);
    __syncthreads();
    mma64x2(T0, T1, T2, wr, wc, lane, acc);
    __syncthreads();
  }
#pragma unroll
  for (int pass = 0; pass < 2; ++pass) {
    acc_store_half(bounce, acc, pass, wr, wc, lane, true);  // relu(y_sparse)
    __syncthreads();
    for (int w = 0; w < 16; ++w) {
      int e = w * 256 + tid;
      int rrel = e >> 6, p = e & 63;
      float ys0 = bounce[rrel * 128 + 2 * p], ys1 = bounce[rrel * 128 + 2 * p + 1];
      int t = t0 + pass * 64 + rrel, pp = jt * 64 + p;
      size_t u32b = (size_t)(h * T_ + t) * 2048 + pp;
      u32 qh = ((const u32*)QRH)[u32b], ql = ((const u32*)QRL)[u32b];
      float qe = b2f((u16)(qh & 0xffff)) + b2f((u16)(ql & 0xffff));
      float qo = b2f((u16)(qh >> 16)) + b2f((u16)(ql >> 16));
      float2 c = trig_ct(csA, csB, t, pp);
      float xe = fmaxf(qe * c.x + qo * c.y, 0.0f);  // inverse rotation; x_sparse >= 0
      float xo = fmaxf(qo * c.x - qe * c.y, 0.0f);
      u32 hi, lo;
      split2(ys0 * xe, ys1 * xo, hi, lo);
      ((u32*)QRH)[u32b] = hi;
      ((u32*)QRL)[u32b] = lo;
    }
    __syncthreads();
  }
}

// G4b: part[ks*4+h] = (xyh+xyl)[ks-half] @ dec_hi[h][ks-half].  2-term, double-buffered.
// grid(16,2,8): z = h + 4*ks.  per-b.
__global__ __launch_bounds__(256) void k_g4b(const u16* __restrict__ xyH,
                                             const u16* __restrict__ xyL,
                                             const u16* __restrict__ dtH,
                                             float* __restrict__ part) {
  GEMM_PRE2D
  int it = blockIdx.x, jt = blockIdx.y;
  int h = blockIdx.z & 3, ks = blockIdx.z >> 2;
  int t0 = it * 128;
  size_t ao = (size_t)(h * T_ + t0) * NN_;
  size_t bo = (size_t)h * D_ * NN_ + (size_t)jt * 128 * NN_;
  int k0 = ks * 32, k1 = ks * 32 + 32;
  {  // prologue
    stage_t(xyH + ao + k0 * 64, NN_, smd, wid, lane);
    stage_t(xyL + ao + k0 * 64, NN_, smd + 8192, wid, lane);
    stage_t(dtH + bo + k0 * 64, NN_, smd + 16384, wid, lane);
  }
  for (int kb = k0; kb < k1; ++kb) {
    short* cur = smd + ((kb - k0) & 1) * 24576;
    __syncthreads();
    if (kb + 1 < k1) {
      short* nxt = smd + ((kb + 1 - k0) & 1) * 24576;
      stage_t(xyH + ao + (kb + 1) * 64, NN_, nxt, wid, lane);
      stage_t(xyL + ao + (kb + 1) * 64, NN_, nxt + 8192, wid, lane);
      stage_t(dtH + bo + (kb + 1) * 64, NN_, nxt + 16384, wid, lane);
    }
    mma64x2(cur, cur + 8192, cur + 16384, wr, wc, lane, acc);
  }
  __syncthreads();
#pragma unroll
  for (int pass = 0; pass < 2; ++pass) {
    acc_store_half(bounce, acc, pass, wr, wc, lane, false);
    __syncthreads();
    for (int w = 0; w < 32; ++w) {
      int e = w * 256 + tid;
      int row = e >> 7, col = e & 127;
      part[((size_t)blockIdx.z * T_ + t0 + pass * 64 + row) * 256 + jt * 128 + col] =
          bounce[row * 128 + col];
    }
    __syncthreads();
  }
}

// LN3: yMLP = sum of 8 part slabs (f32); x = ln(x + ln(yMLP)); refresh x, xb hi/lo. 512 blocks.
__global__ __launch_bounds__(256) void k_ln3(const float* __restrict__ part, float* __restrict__ x,
                                             u16* __restrict__ xbH, u16* __restrict__ xbL) {
  int lane = threadIdx.x & 63, wid = threadIdx.x >> 6;
  int r = blockIdx.x * 4 + wid;
  float a0 = 0, a1 = 0, a2 = 0, a3 = 0;
#pragma unroll
  for (int h = 0; h < 8; ++h) {
    float4 u = ((const float4*)(part + ((size_t)h * T_ + r) * 256))[lane];
    a0 += u.x; a1 += u.y; a2 += u.z; a3 += u.w;
  }
  float m = wsum(a0 + a1 + a2 + a3) * (1.0f / 256.0f);
  float d0 = a0 - m, d1 = a1 - m, d2 = a2 - m, d3 = a3 - m;
  float var = wsum(d0 * d0 + d1 * d1 + d2 * d2 + d3 * d3) * (1.0f / 256.0f);
  float rs = 1.0f / sqrtf(var + 1e-5f);
  float4 xv = ((const float4*)(x + (size_t)r * 256))[lane];
  float s0 = xv.x + d0 * rs, s1 = xv.y + d1 * rs, s2 = xv.z + d2 * rs, s3 = xv.w + d3 * rs;
  float m2 = wsum(s0 + s1 + s2 + s3) * (1.0f / 256.0f);
  float e0 = s0 - m2, e1 = s1 - m2, e2 = s2 - m2, e3 = s3 - m2;
  float var2 = wsum(e0 * e0 + e1 * e1 + e2 * e2 + e3 * e3) * (1.0f / 256.0f);
  float rs2 = 1.0f / sqrtf(var2 + 1e-5f);
  float y0 = e0 * rs2, y1 = e1 * rs2, y2 = e2 * rs2, y3 = e3 * rs2;
  ((float4*)(x + (size_t)r * 256))[lane] = make_float4(y0, y1, y2, y3);
  ushort4 oh, ol;
  oh.x = f2b(y0); ol.x = f2b(y0 - b2f(oh.x));
  oh.y = f2b(y1); ol.y = f2b(y1 - b2f(oh.y));
  oh.z = f2b(y2); ol.z = f2b(y2 - b2f(oh.z));
  oh.w = f2b(y3); ol.w = f2b(y3 - b2f(oh.w));
  ((ushort4*)(xbH + (size_t)r * 256))[lane] = oh;
  ((ushort4*)(xbL + (size_t)r * 256))[lane] = ol;
}

// G5: logits = xb @ lm_head (3-term) -> f32 out (rows offset by b).  grid(16,2), per-b.
__global__ __launch_bounds__(256) void k_g5(const u16* __restrict__ xbH,
                                            const u16* __restrict__ xbL,
                                            const u16* __restrict__ lmH,
                                            const u16* __restrict__ lmL,
                                            float* __restrict__ out) {
  __shared__ float smf[16384];
  short* AsH = (short*)smf;
  short* AsL = AsH + 8192;
  short* BsH = AsH + 16384;
  short* BsL = AsH + 24576;
  int tid = threadIdx.x;
  int lane = tid & 63, wid = tid >> 6;
  int wr = wid >> 1, wc = wid & 1;
  f4 acc[4][4];
  acc_zero(acc);
  int it = blockIdx.x, jt = blockIdx.y;
  size_t ao = (size_t)it * 128 * 256;
  size_t bo = (size_t)jt * 128 * 256;
  for (int kb = 0; kb < 4; ++kb) {
    stage_t(xbH + ao + kb * 64, 256, AsH, wid, lane);
    stage_t(xbL + ao + kb * 64, 256, AsL, wid, lane);
    stage_t(lmH + bo + kb * 64, 256, BsH, wid, lane);
    stage_t(lmL + bo + kb * 64, 256, BsL, wid, lane);
    __syncthreads();
    mma64x3(AsH, AsL, BsH, BsL, wr, wc, lane, acc);
    __syncthreads();
  }
  acc_store_f32(smf, acc, wr, wc, lane, false);
  __syncthreads();
  for (int w = 0; w < 64; ++w) {
    int e = w * 256 + tid;
    int row = e >> 7, col = e & 127;
    out[(size_t)(it * 128 + row) * 256 + jt * 128 + col] = smf[row * 128 + col];
  }
}

extern "C" void kernel_launch(void* const* d_in, const int* in_sizes, int n_in, void* d_out,
                              int out_size, void* d_ws, size_t ws_size, hipStream_t stream) {
  const int*   idx   = (const int*)d_in[0];
  const float* embed = (const float*)d_in[1];
  const float* enc   = (const float*)d_in[2];
  const float* encv  = (const float*)d_in[3];
  const float* dec   = (const float*)d_in[4];
  const float* lm    = (const float*)d_in[5];

  if (ws_size < WS_NEED) {  // sentinel: undersized workspace is diagnosable (bf16-trunc 12672 pattern)
    hipMemsetAsync(d_out, 0x46, (size_t)out_size * 4, stream);
    return;
  }

  char* w = (char*)d_ws;
  float2* csA  = (float2*)(w + CSA_OFF);
  float2* csB  = (float2*)(w + CSB_OFF);
  u16*    etH  = (u16*)(w + ETH_OFF);
  u16*    etL  = (u16*)(w + ETL_OFF);
  u16*    evH  = (u16*)(w + EVH_OFF);
  u16*    evL  = (u16*)(w + EVL_OFF);
  u16*    dtH  = (u16*)(w + DTH_OFF);
  u16*    dtL  = (u16*)(w + DTL_OFF);
  u16*    lmH  = (u16*)(w + LMH_OFF);
  u16*    lmL  = (u16*)(w + LML_OFF);
  float*  x    = (float*)(w + X_OFF);
  u16*    xbH  = (u16*)(w + XBH_OFF);
  u16*    xbL  = (u16*)(w + XBL_OFF);
  u16*    xbTH = (u16*)(w + XBTH_OFF);
  u16*    xbTL = (u16*)(w + XBTL_OFF);
  u16*    QRH  = (u16*)(w + QRH_OFF);
  u16*    QRL  = (u16*)(w + QRL_OFF);
  u16*    SpH  = (u16*)(w + SH_OFF);
  float*  part = (float*)(w + SH_OFF);   // overlays S-hi (S dead after G3); 16MB < 17.8MB
  float*  yKV1 = (float*)(w + SL_OFF);   // freed S-lo region -> g3 partial 1
  float*  yKV0 = (float*)(w + YKV_OFF);
  u16*    ykH  = (u16*)(w + YKBH_OFF);
  u16*    ykL  = (u16*)(w + YKBL_OFF);

  k_costab<<<1152, 256, 0, stream>>>(csA, csB);
  k_tcast2<<<dim3(128, 8, 4), dim3(32, 8), 0, stream>>>(enc, etH, etL, 256, 4096);
  k_tcast2<<<dim3(128, 8, 4), dim3(32, 8), 0, stream>>>(encv, evH, evL, 256, 4096);
  k_tcast2<<<dim3(8, 128, 4), dim3(32, 8), 0, stream>>>(dec, dtH, dtL, 4096, 256);
  k_tcast2<<<dim3(8, 8, 1), dim3(32, 8), 0, stream>>>(lm, lmH, lmL, 256, 256);

  for (int b = 0; b < 2; ++b) {
    k_ln_embed<<<512, 256, 0, stream>>>(idx, embed, b, x, xbH, xbL);
    k_xbt<<<2048, 256, 0, stream>>>(xbH, xbL, xbTH, xbTL);
    for (int l = 0; l < NLAYER; ++l) {
      k_g1<<<dim3(16, 32, 4), 256, 0, stream>>>(xbH, xbL, etH, csA, csB, QRH, QRL);
      k_g2<<<204, 256, 0, stream>>>(QRH, QRL, SpH);
      k_g3<<<dim3(16, 2, 8), 256, 0, stream>>>(SpH, xbTH, xbTL, yKV0, yKV1);
      k_ln_f32<<<2048, 256, 0, stream>>>(yKV0, yKV1, ykH, ykL);
      k_g4a<<<dim3(16, 32, 4), 256, 0, stream>>>(ykH, ykL, evH, csA, csB, QRH, QRL);
      k_g4b<<<dim3(16, 2, 8), 256, 0, stream>>>(QRH, QRL, dtH, part);
      k_ln3<<<512, 256, 0, stream>>>(part, x, xbH, xbL);
      k_xbt<<<2048, 256, 0, stream>>>(xbH, xbL, xbTH, xbTL);
    }
    k_g5<<<dim3(16, 2), 256, 0, stream>>>(xbH, xbL, lmH, lmL, (float*)d_out + (size_t)b * T_ * 256);
  }
}